// Round 1
// baseline (283.340 us; speedup 1.0000x reference)
//
#include <hip/hip_runtime.h>
#include <hip/hip_fp16.h>
#include <math.h>

// ---------------------------------------------------------------------------
// WaveRNN fused, wave-per-item, fp16-LDS + v_dot2_f32_f16 convs.
// Round 7 changes vs round 6 (111 us fused, occupancy 49.5%):
//  (1) 2 items per 128-thread block (one wave per item, disjoint LDS slices).
//      1-wave workgroups were capped by the 16-workgroup/CU slot limit
//      (16 waves/CU = the measured 49.5% occupancy). 2-wave blocks ->
//      LDS-capped 12 blocks/CU x 2 waves = 24 waves/CU (75%).
//  (2) No __syncthreads coupling between the two waves: all phase syncs are
//      per-wave `s_waitcnt lgkmcnt(0)` (DS ops drain; no s_barrier). Waves
//      share nothing in LDS.
//  (3) w_ih rows padded 19->20 fp32 in pack kernel -> GRU loads 5x float4
//      per row instead of 19 scalar dwords.
// Known poisons avoided: no live-across-phase register staging (R3),
// no half-wave-shfl GRU (R3/R4).
// ---------------------------------------------------------------------------

typedef _Float16 h2 __attribute__((ext_vector_type(2)));
typedef _Float16 h4 __attribute__((ext_vector_type(4)));

__device__ __forceinline__ float fdot2(h2 a, h2 b, float c)
{
#if defined(__has_builtin)
#if __has_builtin(__builtin_amdgcn_fdot2)
    return __builtin_amdgcn_fdot2(a, b, c, false);
#else
    return c + (float)a.x * (float)b.x + (float)a.y * (float)b.y;
#endif
#else
    return c + (float)a.x * (float)b.x + (float)a.y * (float)b.y;
#endif
}

// Per-wave phase sync: all LDS traffic is wave-private, so a full lgkmcnt
// drain (DS ops complete in-order w.r.t. lgkmcnt(0)) makes every lane's
// ds_write visible to every lane's subsequent ds_read. The "memory" clobber
// stops the compiler moving LDS ops across it.
__device__ __forceinline__ void wave_sync()
{
    asm volatile("s_waitcnt lgkmcnt(0)" ::: "memory");
}

// Pack conv weights into zero-padded half2 pairs in d_ws:
//   [0,64)    w1p: c(4) x 16 pairs, pair j covers taps (2j-1, 2j)   [tap -1 = 0]
//   [64,320)  w2p: (c*4+ci)(32) x 8 pairs, taps (2j, 2j+1), tap 15 = 0
//   [320,832) w3p: (c*8+ci)(128) x 4 pairs, taps (2j, 2j+1), tap 7 = 0
// plus fp32 region at byte 4096: w_ih padded to (96,20), col 19 = 0.
__global__ void pack_weights(const float* __restrict__ w1,
                             const float* __restrict__ w2,
                             const float* __restrict__ w3,
                             const float* __restrict__ w_ih,
                             h2* __restrict__ ws,
                             float* __restrict__ wihp)
{
    for (int idx = threadIdx.x; idx < 832; idx += 256) {
        float f0, f1;
        if (idx < 64) {
            int c = idx >> 4, jp = idx & 15;
            int j0 = 2 * jp, j1 = j0 + 1;
            f0 = (j0 == 0) ? 0.0f : w1[c * 31 + j0 - 1];
            f1 = w1[c * 31 + j1 - 1];
        } else if (idx < 320) {
            int r = idx - 64, cc = r >> 3, jp = r & 7;
            int j0 = 2 * jp, j1 = j0 + 1;
            f0 = w2[cc * 15 + j0];
            f1 = (j1 < 15) ? w2[cc * 15 + j1] : 0.0f;
        } else {
            int r = idx - 320, cc = r >> 2, jp = r & 3;
            int j0 = 2 * jp, j1 = j0 + 1;
            f0 = (j0 < 7) ? w3[cc * 7 + j0] : 0.0f;
            f1 = (j1 < 7) ? w3[cc * 7 + j1] : 0.0f;
        }
        ws[idx] = (h2){(_Float16)f0, (_Float16)f1};
    }
    for (int idx = threadIdx.x; idx < 96 * 20; idx += 256) {
        int r = idx / 20, c = idx % 20;
        wihp[idx] = (c < 19) ? w_ih[r * 19 + c] : 0.0f;
    }
}

// conv1 at position p: window = stored halfs [h0 .. h0+31]; pair j covers
// (h0+2j, h0+2j+1); w1p pair 0 = (0, w[0]) absorbs the odd window start.
__device__ __forceinline__ void conv1_pos(const _Float16* __restrict__ xh,
                                          _Float16* __restrict__ y1h,
                                          const h2* __restrict__ w1p,
                                          const float* __restrict__ b1,
                                          int p, int h0)
{
    const h4* src = (const h4*)(xh + h0);        // byte 2*h0, 8B aligned
    h2 xp[16];
#pragma unroll
    for (int j = 0; j < 8; ++j) {
        h4 v = src[j];
        xp[2 * j]     = (h2){v.x, v.y};
        xp[2 * j + 1] = (h2){v.z, v.w};
    }
    float a0 = b1[0], a1 = b1[1], a2 = b1[2], a3 = b1[3];
#pragma unroll
    for (int j = 0; j < 16; ++j) {
        a0 = fdot2(xp[j], w1p[j],      a0);
        a1 = fdot2(xp[j], w1p[16 + j], a1);
        a2 = fdot2(xp[j], w1p[32 + j], a2);
        a3 = fdot2(xp[j], w1p[48 + j], a3);
    }
    y1h[7 + p]        = (_Float16)fmaxf(a0, 0.0f);
    y1h[512 + 7 + p]  = (_Float16)fmaxf(a1, 0.0f);
    y1h[1024 + 7 + p] = (_Float16)fmaxf(a2, 0.0f);
    y1h[1536 + 7 + p] = (_Float16)fmaxf(a3, 0.0f);
}

__global__ void __launch_bounds__(128, 6)
wavernn_fused(const float* __restrict__ past,      // (B,2000)
              const float* __restrict__ velocity,  // (B,)
              const float* __restrict__ log_pitch, // (B,)
              const float* __restrict__ time_in,   // (B,)
              const float* __restrict__ hidden,    // (B,32)
              const float* __restrict__ b1,
              const float* __restrict__ b2,
              const float* __restrict__ b3,
              const float* __restrict__ wihp,      // packed (96,20) fp32
              const float* __restrict__ w_hh,
              const float* __restrict__ b_ih, const float* __restrict__ b_hh,
              const float* __restrict__ w_proj, const float* __restrict__ b_proj,
              const h2* __restrict__ wsp,          // packed conv weights
              float* __restrict__ out, int B)
{
    // Per-wave slices: wave w of the block owns [w] of each array.
    __shared__ __align__(16) _Float16 Xs[2][1056];   // xbuf -> y2s -> gis|ghs
    __shared__ __align__(16) _Float16 y1s[2][2048];  // 4 ch x [pad7|500|pad5]
    __shared__ float rnns[2][20];  // [0..15]=ctx, 16=vel, 17=pitch, 18=time, 19=0
    __shared__ float hss[2][32];

    const int w = threadIdx.x >> 6;   // wave id within block
    const int t = threadIdx.x & 63;   // lane
    const int b = blockIdx.x * 2 + w;
    if (b >= B) return;               // no inter-wave barriers -> safe

    _Float16* const xbuf = &Xs[w][0];             // conv1 phase
    _Float16* const y2h  = &Xs[w][0];             // conv2/3 phase
    float* const gis     = (float*)&Xs[w][0];     // GRU phase
    float* const ghs     = (float*)&Xs[w][0] + 96;
    _Float16* const y1h  = &y1s[w][0];
    float* const rnn     = &rnns[w][0];
    float* const hs      = &hss[w][0];

    const h2* const w1p = wsp;
    const h2* const w2p = wsp + 64;
    const h2* const w3p = wsp + 320;

    const float4* row4 = (const float4*)(past + (size_t)b * 2000);

    // ---------------- pads + small stages + chunk0 stage ----------------
    if (t < 16) { xbuf[t] = (_Float16)0.0f; xbuf[1032 + t] = (_Float16)0.0f; }
    if (t < 48) { int c = t / 12, k = t % 12;
                  y1h[c * 512 + (k < 7 ? k : 500 + k)] = (_Float16)0.0f; }
    if (t < 32) hs[t] = hidden[(size_t)b * 32 + t];
    if (t == 0) rnn[16] = velocity[b];
    if (t == 1) rnn[17] = log_pitch[b];
    if (t == 2) rnn[18] = time_in[b];
    if (t == 3) rnn[19] = 0.0f;

    // chunk0: samples 0..1015 at half idx 16+s (write h4 = 8B aligned)
#pragma unroll
    for (int j = 0; j < 4; ++j) {
        int i = t + 64 * j;
        if (i < 254) {
            float4 q = row4[i];
            h4 hv = {(_Float16)q.x, (_Float16)q.y, (_Float16)q.z, (_Float16)q.w};
            *(h4*)(xbuf + 16 + 4 * i) = hv;
        }
    }
    wave_sync();

    // ---------------- conv1 chunk 0: positions 0..249, h0 = 4p ----------
#pragma unroll
    for (int j = 0; j < 4; ++j) {
        int p = t + 64 * j;
        if (p < 250) conv1_pos(xbuf, y1h, w1p, b1, p, 4 * p);
    }
    wave_sync();                     // WAR: all reads of xbuf done

    // ---------------- stage chunk 1: samples 984..1999 at idx 16+(s-984) --
#pragma unroll
    for (int j = 0; j < 4; ++j) {
        int i = t + 64 * j;
        if (i < 254) {
            float4 q = row4[246 + i];
            h4 hv = {(_Float16)q.x, (_Float16)q.y, (_Float16)q.z, (_Float16)q.w};
            *(h4*)(xbuf + 16 + 4 * i) = hv;
        }
    }
    wave_sync();

    // ---------------- conv1 chunk 1: positions 250..499, h0 = 4p-984 ------
#pragma unroll
    for (int j = 0; j < 4; ++j) {
        int p = 250 + t + 64 * j;
        if (p < 500) conv1_pos(xbuf, y1h, w1p, b1, p, 4 * p - 984);
    }
    wave_sync();                     // xbuf dead; X becomes y2h

    // ---------------- conv2: 4->8ch, k=15, s=4 (+ y2h pad zeroing) --------
    if (t < 56) { int c = t / 7, k = t % 7;
                  y2h[c * 132 + (k < 3 ? k : 125 + k)] = (_Float16)0.0f; }
#pragma unroll
    for (int jj = 0; jj < 2; ++jj) {
        int p = t + 64 * jj;
        if (p < 125) {
            float acc[8];
#pragma unroll
            for (int c = 0; c < 8; ++c) acc[c] = b2[c];
#pragma unroll
            for (int ci = 0; ci < 4; ++ci) {
                // window = stored halfs [4p .. 4p+15] (taps 0..14 + pad)
                const h4* src = (const h4*)(y1h + 512 * ci + 4 * p);
                h2 xp[8];
#pragma unroll
                for (int j = 0; j < 4; ++j) {
                    h4 v = src[j];
                    xp[2 * j]     = (h2){v.x, v.y};
                    xp[2 * j + 1] = (h2){v.z, v.w};
                }
#pragma unroll
                for (int jp = 0; jp < 8; ++jp) {
#pragma unroll
                    for (int c = 0; c < 8; ++c)
                        acc[c] = fdot2(xp[jp], w2p[(c * 4 + ci) * 8 + jp], acc[c]);
                }
            }
#pragma unroll
            for (int c = 0; c < 8; ++c)
                y2h[c * 132 + 3 + p] = (_Float16)fmaxf(acc[c], 0.0f);
        }
    }
    wave_sync();

    // ------- conv3: 8->16ch, k=7, s=4 + relu + mean (lanes 0..31) ----------
    if (t < 32) {
        float acc[16];
#pragma unroll
        for (int c = 0; c < 16; ++c) acc[c] = 0.0f;
#pragma unroll
        for (int ci = 0; ci < 8; ++ci) {
            // window = stored halfs [4t .. 4t+7] (taps 0..6 + pad)
            const h4* src = (const h4*)(y2h + 132 * ci + 4 * t);
            h4 v0 = src[0], v1 = src[1];
            h2 xp[4] = {(h2){v0.x, v0.y}, (h2){v0.z, v0.w},
                        (h2){v1.x, v1.y}, (h2){v1.z, v1.w}};
#pragma unroll
            for (int jp = 0; jp < 4; ++jp) {
#pragma unroll
                for (int c = 0; c < 16; ++c)
                    acc[c] = fdot2(xp[jp], w3p[(c * 8 + ci) * 4 + jp], acc[c]);
            }
        }
#pragma unroll
        for (int c = 0; c < 16; ++c) {
            float v = fmaxf(acc[c] + b3[c], 0.0f);
            v += __shfl_xor(v, 16); v += __shfl_xor(v, 8);
            v += __shfl_xor(v, 4);  v += __shfl_xor(v, 2);
            v += __shfl_xor(v, 1);
            if (t == 0) rnn[c] = v * (1.0f / 32.0f);
        }
    }
    wave_sync();                    // y2h dead; X becomes gis|ghs

    // ---------------- GRU gates (round-2 structure, LDS-based) -------------
    {
        float rv[20];
#pragma unroll
        for (int j = 0; j < 20; ++j) rv[j] = rnn[j];   // rv[19] = 0 pad

        float a = b_ih[t];
        const float4* wr = (const float4*)(wihp + t * 20);
#pragma unroll
        for (int j = 0; j < 5; ++j) {
            float4 q = wr[j];
            a += rv[4 * j] * q.x + rv[4 * j + 1] * q.y +
                 rv[4 * j + 2] * q.z + rv[4 * j + 3] * q.w;
        }
        gis[t] = a;
        if (t < 32) {
            float a2 = b_ih[64 + t];
            const float4* wr2 = (const float4*)(wihp + (64 + t) * 20);
#pragma unroll
            for (int j = 0; j < 5; ++j) {
                float4 q = wr2[j];
                a2 += rv[4 * j] * q.x + rv[4 * j + 1] * q.y +
                      rv[4 * j + 2] * q.z + rv[4 * j + 3] * q.w;
            }
            gis[64 + t] = a2;
        }

        float hv[32];
#pragma unroll
        for (int j = 0; j < 32; ++j) hv[j] = hs[j];

        float g = b_hh[t];
        const float4* wh = (const float4*)(w_hh + t * 32);
#pragma unroll
        for (int j = 0; j < 8; ++j) {
            float4 q = wh[j];
            g += hv[4 * j] * q.x + hv[4 * j + 1] * q.y +
                 hv[4 * j + 2] * q.z + hv[4 * j + 3] * q.w;
        }
        ghs[t] = g;
        if (t < 32) {
            float g2 = b_hh[64 + t];
            const float4* wh2 = (const float4*)(w_hh + (64 + t) * 32);
#pragma unroll
            for (int j = 0; j < 8; ++j) {
                float4 q = wh2[j];
                g2 += hv[4 * j] * q.x + hv[4 * j + 1] * q.y +
                      hv[4 * j + 2] * q.z + hv[4 * j + 3] * q.w;
            }
            ghs[64 + t] = g2;
        }
    }
    wave_sync();

    // ---------------- combine + projection (lanes 0..31) ----------------
    if (t < 32) {
        const int j = t;
        float r = 1.0f / (1.0f + expf(-(gis[j] + ghs[j])));
        float z = 1.0f / (1.0f + expf(-(gis[32 + j] + ghs[32 + j])));
        float n = tanhf(gis[64 + j] + r * ghs[64 + j]);
        float nh = (1.0f - z) * n + z * hs[j];
        out[(size_t)2 * B + (size_t)b * 32 + j] = nh;   // new_hidden

        float p0 = nh * w_proj[j];
        float p1 = nh * w_proj[32 + j];
        p0 += __shfl_xor(p0, 16); p1 += __shfl_xor(p1, 16);
        p0 += __shfl_xor(p0, 8);  p1 += __shfl_xor(p1, 8);
        p0 += __shfl_xor(p0, 4);  p1 += __shfl_xor(p1, 4);
        p0 += __shfl_xor(p0, 2);  p1 += __shfl_xor(p1, 2);
        p0 += __shfl_xor(p0, 1);  p1 += __shfl_xor(p1, 1);
        if (j == 0) {
            out[b] = p0 + b_proj[0];                    // mu
            out[B + b] = expf(p1 + b_proj[1]);          // sigma
        }
    }
}

extern "C" void kernel_launch(void* const* d_in, const int* in_sizes, int n_in,
                              void* d_out, int out_size, void* d_ws, size_t ws_size,
                              hipStream_t stream)
{
    const float* past      = (const float*)d_in[0];
    const float* velocity  = (const float*)d_in[1];
    const float* log_pitch = (const float*)d_in[2];
    const float* time_in   = (const float*)d_in[3];
    const float* hidden    = (const float*)d_in[4];
    const float* w1  = (const float*)d_in[5];
    const float* b1  = (const float*)d_in[6];
    const float* w2  = (const float*)d_in[7];
    const float* b2  = (const float*)d_in[8];
    const float* w3  = (const float*)d_in[9];
    const float* b3  = (const float*)d_in[10];
    const float* wih = (const float*)d_in[11];
    const float* whh = (const float*)d_in[12];
    const float* bih = (const float*)d_in[13];
    const float* bhh = (const float*)d_in[14];
    const float* wpr = (const float*)d_in[15];
    const float* bpr = (const float*)d_in[16];

    const int B = in_sizes[0] / 2000;
    h2* wsp = (h2*)d_ws;
    float* wihp = (float*)((char*)d_ws + 4096);   // (96,20) fp32, 7680 B

    pack_weights<<<dim3(1), dim3(256), 0, stream>>>(w1, w2, w3, wih, wsp, wihp);

    wavernn_fused<<<dim3((B + 1) / 2), dim3(128), 0, stream>>>(
        past, velocity, log_pitch, time_in, hidden,
        b1, b2, b3, wihp, whh, bih, bhh, wpr, bpr,
        (const h2*)wsp, (float*)d_out, B);
}

// Round 2
// 257.055 us; speedup vs baseline: 1.1023x; 1.1023x over previous
//
#include <hip/hip_runtime.h>
#include <hip/hip_fp16.h>
#include <math.h>

// ---------------------------------------------------------------------------
// WaveRNN fused, wave-per-item. Round 8:
//  - Geometry reverted to R6/R0 proven shape: 64-thread single-wave blocks,
//    __syncthreads, 6416 B LDS, 16 blocks/CU. (R7's 2-wave blocks regressed.)
//  - conv1 unchanged (fp16 LDS + v_dot2, efficient: 4 parallel channel accs).
//  - conv2 + conv3 moved to MFMA (v_mfma_f32_16x16x32_f16):
//      conv2: C[8][125] = W[8][60] X[60][125] -> 8 tiles x 2 ksteps = 16 MFMA
//      conv3: C[16][32] = W[16][56] X[56][32] -> 2 tiles x 2 ksteps = 4 MFMA
//    replacing 1024 v_dot2 wave-instrs (~2/3 of all conv VALU work).
//    B-fragments (k-octet = 8 contiguous taps) are 16 contiguous bytes of
//    y1h/y2h -> 2x ds_read_b64 per fragment, no im2col buffer.
//    A-fragments (weights, item-invariant) packed per-lane by prep kernel,
//    one global_load_dwordx4 per kstep, loaded inside the phase (no
//    live-across-phase staging -- R3 poison).
//    Zero-padded taps live in the A (weight) operand, so out-of-range B
//    reads only ever multiply zero weights or feed discarded outputs.
// Known poisons avoided: no live-across-phase register staging (R3),
// no half-wave-shfl GRU (R3/R4), no multi-wave blocks (R7).
// ---------------------------------------------------------------------------

typedef _Float16 h2 __attribute__((ext_vector_type(2)));
typedef _Float16 h4 __attribute__((ext_vector_type(4)));
typedef _Float16 h8 __attribute__((ext_vector_type(8)));
typedef float f4 __attribute__((ext_vector_type(4)));

__device__ __forceinline__ float fdot2(h2 a, h2 b, float c)
{
#if defined(__has_builtin)
#if __has_builtin(__builtin_amdgcn_fdot2)
    return __builtin_amdgcn_fdot2(a, b, c, false);
#else
    return c + (float)a.x * (float)b.x + (float)a.y * (float)b.y;
#endif
#else
    return c + (float)a.x * (float)b.x + (float)a.y * (float)b.y;
#endif
}

__device__ __forceinline__ h8 ld_b8(const _Float16* p)
{
    h4 lo = *(const h4*)p;
    h4 hi = *(const h4*)(p + 4);
    return (h8){lo.x, lo.y, lo.z, lo.w, hi.x, hi.y, hi.z, hi.w};
}

// d_ws layout (halfs unless noted):
//   [0,128)        w1p: c(4) x 16 h2 pairs (conv1, dot2 path)
//   half 1024      wfrag2: [kk(2)][lane(64)][8]  A-frags conv2 (W2 16x64, M-pad)
//   half 2048      wfrag3: [kk(2)][lane(64)][8]  A-frags conv3 (W3 16x64)
//   byte 8192      wihp: (96,20) fp32, col 19 = 0
__global__ void pack_weights(const float* __restrict__ w1,
                             const float* __restrict__ w2,
                             const float* __restrict__ w3,
                             const float* __restrict__ w_ih,
                             _Float16* __restrict__ hws,
                             float* __restrict__ wihp)
{
    // conv1 dot2 pairs: pair j covers taps (2j-1, 2j) [tap -1 = 0]
    for (int idx = threadIdx.x; idx < 64; idx += 256) {
        int c = idx >> 4, jp = idx & 15;
        int j0 = 2 * jp, j1 = j0 + 1;
        float f0 = (j0 == 0) ? 0.0f : w1[c * 31 + j0 - 1];
        float f1 = w1[c * 31 + j1 - 1];
        hws[2 * idx]     = (_Float16)f0;
        hws[2 * idx + 1] = (_Float16)f1;
    }
    // conv2 A-fragments: A[m=c][k = ci*16 + tap], rows 8..15 and tap 15 = 0
    for (int i = threadIdx.x; i < 1024; i += 256) {
        int kk = i >> 9, l = (i >> 3) & 63, j = i & 7;
        int c = l & 15, k = kk * 32 + ((l >> 4) << 3) + j;
        int ci = k >> 4, tap = k & 15;
        float v = (c < 8 && tap < 15) ? w2[(c * 4 + ci) * 15 + tap] : 0.0f;
        hws[1024 + i] = (_Float16)v;
    }
    // conv3 A-fragments: A[m=c][k = ci*8 + tap], tap 7 = 0
    for (int i = threadIdx.x; i < 1024; i += 256) {
        int kk = i >> 9, l = (i >> 3) & 63, j = i & 7;
        int c = l & 15, k = kk * 32 + ((l >> 4) << 3) + j;
        int ci = k >> 3, tap = k & 7;
        float v = (tap < 7) ? w3[(c * 8 + ci) * 7 + tap] : 0.0f;
        hws[2048 + i] = (_Float16)v;
    }
    // GRU w_ih padded to rows of 20 floats
    for (int idx = threadIdx.x; idx < 96 * 20; idx += 256) {
        int r = idx / 20, c = idx % 20;
        wihp[idx] = (c < 19) ? w_ih[r * 19 + c] : 0.0f;
    }
}

// conv1 at position p: window = stored halfs [h0 .. h0+31]; pair j covers
// (h0+2j, h0+2j+1); w1p pair 0 = (0, w[0]) absorbs the odd window start.
__device__ __forceinline__ void conv1_pos(const _Float16* __restrict__ xh,
                                          _Float16* __restrict__ y1h,
                                          const h2* __restrict__ w1p,
                                          const float* __restrict__ b1,
                                          int p, int h0)
{
    const h4* src = (const h4*)(xh + h0);        // byte 2*h0, 8B aligned
    h2 xp[16];
#pragma unroll
    for (int j = 0; j < 8; ++j) {
        h4 v = src[j];
        xp[2 * j]     = (h2){v.x, v.y};
        xp[2 * j + 1] = (h2){v.z, v.w};
    }
    float a0 = b1[0], a1 = b1[1], a2 = b1[2], a3 = b1[3];
#pragma unroll
    for (int j = 0; j < 16; ++j) {
        a0 = fdot2(xp[j], w1p[j],      a0);
        a1 = fdot2(xp[j], w1p[16 + j], a1);
        a2 = fdot2(xp[j], w1p[32 + j], a2);
        a3 = fdot2(xp[j], w1p[48 + j], a3);
    }
    y1h[7 + p]        = (_Float16)fmaxf(a0, 0.0f);
    y1h[512 + 7 + p]  = (_Float16)fmaxf(a1, 0.0f);
    y1h[1024 + 7 + p] = (_Float16)fmaxf(a2, 0.0f);
    y1h[1536 + 7 + p] = (_Float16)fmaxf(a3, 0.0f);
}

__global__ void __launch_bounds__(64, 3)
wavernn_fused(const float* __restrict__ past,      // (B,2000)
              const float* __restrict__ velocity,  // (B,)
              const float* __restrict__ log_pitch, // (B,)
              const float* __restrict__ time_in,   // (B,)
              const float* __restrict__ hidden,    // (B,32)
              const float* __restrict__ b1,
              const float* __restrict__ b2,
              const float* __restrict__ b3,
              const float* __restrict__ wihp,      // packed (96,20) fp32
              const float* __restrict__ w_hh,
              const float* __restrict__ b_ih, const float* __restrict__ b_hh,
              const float* __restrict__ w_proj, const float* __restrict__ b_proj,
              const _Float16* __restrict__ hws,    // packed weights (halfs)
              float* __restrict__ out, int B)
{
    __shared__ __align__(16) _Float16 X[1056];    // xbuf -> y2s -> gis|ghs
    __shared__ __align__(16) _Float16 y1h[2048];  // 4 ch x [pad7|500|pad5]
    __shared__ float rnn[20];   // [0..15]=ctx, 16=vel, 17=pitch, 18=time, 19=0
    __shared__ float hs[32];

    _Float16* const xbuf = X;                     // conv1 phase
    _Float16* const y2h  = X;                     // conv2/3 phase
    float* const gis     = (float*)X;             // GRU phase
    float* const ghs     = (float*)X + 96;

    const h2* const w1p = (const h2*)hws;
    const h8* const wf2 = (const h8*)(hws + 1024);   // [kk][lane]
    const h8* const wf3 = (const h8*)(hws + 2048);

    const int t = threadIdx.x;       // 0..63, single wave
    const int b = blockIdx.x;

    const float4* row4 = (const float4*)(past + (size_t)b * 2000);

    // ---------------- pads + small stages + chunk0 stage ----------------
    if (t < 16) { xbuf[t] = (_Float16)0.0f; xbuf[1032 + t] = (_Float16)0.0f; }
    if (t < 48) { int c = t / 12, k = t % 12;
                  y1h[c * 512 + (k < 7 ? k : 500 + k)] = (_Float16)0.0f; }
    if (t < 32) hs[t] = hidden[(size_t)b * 32 + t];
    if (t == 0) rnn[16] = velocity[b];
    if (t == 1) rnn[17] = log_pitch[b];
    if (t == 2) rnn[18] = time_in[b];
    if (t == 3) rnn[19] = 0.0f;

    // chunk0: samples 0..1015 at half idx 16+s (write h4 = 8B aligned)
#pragma unroll
    for (int j = 0; j < 4; ++j) {
        int i = t + 64 * j;
        if (i < 254) {
            float4 q = row4[i];
            h4 hv = {(_Float16)q.x, (_Float16)q.y, (_Float16)q.z, (_Float16)q.w};
            *(h4*)(xbuf + 16 + 4 * i) = hv;
        }
    }
    __syncthreads();

    // ---------------- conv1 chunk 0: positions 0..249, h0 = 4p ----------
#pragma unroll
    for (int j = 0; j < 4; ++j) {
        int p = t + 64 * j;
        if (p < 250) conv1_pos(xbuf, y1h, w1p, b1, p, 4 * p);
    }
    __syncthreads();                 // WAR: all reads of xbuf done

    // ---------------- stage chunk 1: samples 984..1999 at idx 16+(s-984) --
#pragma unroll
    for (int j = 0; j < 4; ++j) {
        int i = t + 64 * j;
        if (i < 254) {
            float4 q = row4[246 + i];
            h4 hv = {(_Float16)q.x, (_Float16)q.y, (_Float16)q.z, (_Float16)q.w};
            *(h4*)(xbuf + 16 + 4 * i) = hv;
        }
    }
    __syncthreads();

    // ---------------- conv1 chunk 1: positions 250..499, h0 = 4p-984 ------
#pragma unroll
    for (int j = 0; j < 4; ++j) {
        int p = 250 + t + 64 * j;
        if (p < 500) conv1_pos(xbuf, y1h, w1p, b1, p, 4 * p - 984);
    }
    __syncthreads();                 // xbuf dead; X becomes y2h

    // ---------------- conv2 via MFMA: C[8][125] = W[8][60] X[60][125] -----
    // B-frag: lane l -> (n = tile*16 + (l&15), k-octet = l>>4).
    // kk0 octets: (ci0,t0-7)(ci0,t8-15)(ci1,t0-7)(ci1,t8-15); kk1: ci+2.
    // Stored-half window base for position p is 4p (pad7 layout), so the
    // k-octet's 8 taps are halfs [512*ci + 4p + t0, +8) -- contiguous.
    if (t < 56) { int c = t / 7, k = t % 7;
                  y2h[c * 132 + (k < 3 ? k : 125 + k)] = (_Float16)0.0f; }
    {
        const int o = t >> 4, q = t & 15;
        const int ci0 = o >> 1, tp0 = (o & 1) * 8;
        float b2v[4];
#pragma unroll
        for (int r = 0; r < 4; ++r) b2v[r] = b2[(o * 4 + r) & 7];
        const h8 a0 = wf2[t];        // kk = 0
        const h8 a1 = wf2[64 + t];   // kk = 1
#pragma unroll
        for (int T = 0; T < 8; ++T) {
            const int p = T * 16 + q;
            h8 x0 = ld_b8(y1h + 512 * ci0 + 4 * p + tp0);
            h8 x1 = ld_b8(y1h + 512 * (ci0 + 2) + 4 * p + tp0);
            f4 acc = {0.0f, 0.0f, 0.0f, 0.0f};
            acc = __builtin_amdgcn_mfma_f32_16x16x32_f16(a0, x0, acc, 0, 0, 0);
            acc = __builtin_amdgcn_mfma_f32_16x16x32_f16(a1, x1, acc, 0, 0, 0);
            // D: row (=channel) = o*4+r, col (=position) = q; rows 0..7 valid
            if (t < 32 && p < 125) {
#pragma unroll
                for (int r = 0; r < 4; ++r)
                    y2h[(o * 4 + r) * 132 + 3 + p] =
                        (_Float16)fmaxf(acc[r] + b2v[r], 0.0f);
            }
        }
    }
    __syncthreads();

    // ------- conv3 via MFMA: C[16][32] = W[16][56] X[56][32], + mean ------
    // k = ci*8 + tap; kk0 -> ci = l>>4, kk1 -> ci = 4 + (l>>4).
    // relu(D + b3) per element, then mean over 32 positions (2 tiles).
    {
        const int o = t >> 4, q = t & 15;
        float b3v[4];
#pragma unroll
        for (int r = 0; r < 4; ++r) b3v[r] = b3[o * 4 + r];
        const h8 a0 = wf3[t];        // kk = 0
        const h8 a1 = wf3[64 + t];   // kk = 1
        h8 x00 = ld_b8(y2h + 132 * o + 4 * q);              // tile0 kk0
        h8 x01 = ld_b8(y2h + 132 * (4 + o) + 4 * q);        // tile0 kk1
        h8 x10 = ld_b8(y2h + 132 * o + 4 * (16 + q));       // tile1 kk0
        h8 x11 = ld_b8(y2h + 132 * (4 + o) + 4 * (16 + q)); // tile1 kk1
        const f4 z = {0.0f, 0.0f, 0.0f, 0.0f};
        f4 d0 = __builtin_amdgcn_mfma_f32_16x16x32_f16(a0, x00, z, 0, 0, 0);
        d0 = __builtin_amdgcn_mfma_f32_16x16x32_f16(a1, x01, d0, 0, 0, 0);
        f4 d1 = __builtin_amdgcn_mfma_f32_16x16x32_f16(a0, x10, z, 0, 0, 0);
        d1 = __builtin_amdgcn_mfma_f32_16x16x32_f16(a1, x11, d1, 0, 0, 0);
#pragma unroll
        for (int r = 0; r < 4; ++r) {
            float v = fmaxf(d0[r] + b3v[r], 0.0f) + fmaxf(d1[r] + b3v[r], 0.0f);
            v += __shfl_xor(v, 1); v += __shfl_xor(v, 2);
            v += __shfl_xor(v, 4); v += __shfl_xor(v, 8);
            if (q == 0) rnn[o * 4 + r] = v * (1.0f / 32.0f);
        }
    }
    __syncthreads();                // y2h dead; X becomes gis|ghs

    // ---------------- GRU gates (LDS-based) -------------------------------
    {
        float rv[20];
#pragma unroll
        for (int j = 0; j < 20; ++j) rv[j] = rnn[j];   // rv[19] = 0 pad

        float a = b_ih[t];
        const float4* wr = (const float4*)(wihp + t * 20);
#pragma unroll
        for (int j = 0; j < 5; ++j) {
            float4 q = wr[j];
            a += rv[4 * j] * q.x + rv[4 * j + 1] * q.y +
                 rv[4 * j + 2] * q.z + rv[4 * j + 3] * q.w;
        }
        gis[t] = a;
        if (t < 32) {
            float a2 = b_ih[64 + t];
            const float4* wr2 = (const float4*)(wihp + (64 + t) * 20);
#pragma unroll
            for (int j = 0; j < 5; ++j) {
                float4 q = wr2[j];
                a2 += rv[4 * j] * q.x + rv[4 * j + 1] * q.y +
                      rv[4 * j + 2] * q.z + rv[4 * j + 3] * q.w;
            }
            gis[64 + t] = a2;
        }

        float hv[32];
#pragma unroll
        for (int j = 0; j < 32; ++j) hv[j] = hs[j];

        float g = b_hh[t];
        const float4* wh = (const float4*)(w_hh + t * 32);
#pragma unroll
        for (int j = 0; j < 8; ++j) {
            float4 q = wh[j];
            g += hv[4 * j] * q.x + hv[4 * j + 1] * q.y +
                 hv[4 * j + 2] * q.z + hv[4 * j + 3] * q.w;
        }
        ghs[t] = g;
        if (t < 32) {
            float g2 = b_hh[64 + t];
            const float4* wh2 = (const float4*)(w_hh + (64 + t) * 32);
#pragma unroll
            for (int j = 0; j < 8; ++j) {
                float4 q = wh2[j];
                g2 += hv[4 * j] * q.x + hv[4 * j + 1] * q.y +
                      hv[4 * j + 2] * q.z + hv[4 * j + 3] * q.w;
            }
            ghs[64 + t] = g2;
        }
    }
    __syncthreads();

    // ---------------- combine + projection (lanes 0..31) ----------------
    if (t < 32) {
        const int j = t;
        float r = 1.0f / (1.0f + expf(-(gis[j] + ghs[j])));
        float z = 1.0f / (1.0f + expf(-(gis[32 + j] + ghs[32 + j])));
        float n = tanhf(gis[64 + j] + r * ghs[64 + j]);
        float nh = (1.0f - z) * n + z * hs[j];
        out[(size_t)2 * B + (size_t)b * 32 + j] = nh;   // new_hidden

        float p0 = nh * w_proj[j];
        float p1 = nh * w_proj[32 + j];
        p0 += __shfl_xor(p0, 16); p1 += __shfl_xor(p1, 16);
        p0 += __shfl_xor(p0, 8);  p1 += __shfl_xor(p1, 8);
        p0 += __shfl_xor(p0, 4);  p1 += __shfl_xor(p1, 4);
        p0 += __shfl_xor(p0, 2);  p1 += __shfl_xor(p1, 2);
        p0 += __shfl_xor(p0, 1);  p1 += __shfl_xor(p1, 1);
        if (j == 0) {
            out[b] = p0 + b_proj[0];                    // mu
            out[B + b] = expf(p1 + b_proj[1]);          // sigma
        }
    }
}

extern "C" void kernel_launch(void* const* d_in, const int* in_sizes, int n_in,
                              void* d_out, int out_size, void* d_ws, size_t ws_size,
                              hipStream_t stream)
{
    const float* past      = (const float*)d_in[0];
    const float* velocity  = (const float*)d_in[1];
    const float* log_pitch = (const float*)d_in[2];
    const float* time_in   = (const float*)d_in[3];
    const float* hidden    = (const float*)d_in[4];
    const float* w1  = (const float*)d_in[5];
    const float* b1  = (const float*)d_in[6];
    const float* w2  = (const float*)d_in[7];
    const float* b2  = (const float*)d_in[8];
    const float* w3  = (const float*)d_in[9];
    const float* b3  = (const float*)d_in[10];
    const float* wih = (const float*)d_in[11];
    const float* whh = (const float*)d_in[12];
    const float* bih = (const float*)d_in[13];
    const float* bhh = (const float*)d_in[14];
    const float* wpr = (const float*)d_in[15];
    const float* bpr = (const float*)d_in[16];

    const int B = in_sizes[0] / 2000;
    _Float16* hws = (_Float16*)d_ws;
    float* wihp = (float*)((char*)d_ws + 8192);   // (96,20) fp32, 7680 B

    pack_weights<<<dim3(1), dim3(256), 0, stream>>>(w1, w2, w3, wih, hws, wihp);

    wavernn_fused<<<dim3(B), dim3(64), 0, stream>>>(
        past, velocity, log_pitch, time_in, hidden,
        b1, b2, b3, wihp, whh, bih, bhh, wpr, bpr,
        (const _Float16*)hws, (float*)d_out, B);
}